// Round 1
// baseline (62.502 us; speedup 1.0000x reference)
//
#include <hip/hip_runtime.h>

// Bit2Num, B=4: out[j] = (8*x[4j] + 4*x[4j+1] + 2*x[4j+2] + x[4j+3] + 0.5) / 16
// Pure streaming, memory-bound. Each thread: 4x float4 loads (64B) -> 1x float4 store (16B).

__global__ __launch_bounds__(256) void bit2num_b4_kernel(
    const float4* __restrict__ x,   // viewed as float4: x4[k] = x[4k .. 4k+3]
    float4* __restrict__ out,       // viewed as float4: 4 outputs per store
    int n_out4)                     // number of float4 output elements
{
    int i = blockIdx.x * blockDim.x + threadIdx.x;
    const int stride = gridDim.x * blockDim.x;
    for (; i < n_out4; i += stride) {
        const float4 a = x[i * 4 + 0];
        const float4 b = x[i * 4 + 1];
        const float4 c = x[i * 4 + 2];
        const float4 d = x[i * 4 + 3];
        float4 o;
        o.x = fmaf(8.f, a.x, fmaf(4.f, a.y, fmaf(2.f, a.z, a.w + 0.5f))) * 0.0625f;
        o.y = fmaf(8.f, b.x, fmaf(4.f, b.y, fmaf(2.f, b.z, b.w + 0.5f))) * 0.0625f;
        o.z = fmaf(8.f, c.x, fmaf(4.f, c.y, fmaf(2.f, c.z, c.w + 0.5f))) * 0.0625f;
        o.w = fmaf(8.f, d.x, fmaf(2.f, d.z, fmaf(4.f, d.y, d.w + 0.5f))) * 0.0625f;
        out[i] = o;
    }
}

extern "C" void kernel_launch(void* const* d_in, const int* in_sizes, int n_in,
                              void* d_out, int out_size, void* d_ws, size_t ws_size,
                              hipStream_t stream) {
    const float* x = (const float*)d_in[0];
    float* out = (float*)d_out;

    // out_size = batch * N (B=4 groups per output element)
    const int n_out4 = out_size / 4;  // each thread handles 4 outputs (one float4)

    const int block = 256;
    int grid = (n_out4 + block - 1) / block;
    const int max_grid = 256 * 8;  // 256 CUs x 8 blocks/CU, grid-stride the rest
    if (grid > max_grid) grid = max_grid;

    bit2num_b4_kernel<<<grid, block, 0, stream>>>(
        (const float4*)x, (float4*)out, n_out4);
}

// Round 3
// 56.520 us; speedup vs baseline: 1.1058x; 1.1058x over previous
//
#include <hip/hip_runtime.h>

// Bit2Num, B=4: out[j] = (8*x[4j] + 4*x[4j+1] + 2*x[4j+2] + x[4j+3] + 0.5) / 16
// Memory-bound streaming op. Canonical coalescing: one float4-group (= 4 bits
// = 1 output) per lane. Per load instruction the wave reads 1024 contiguous
// bytes; per store it writes 256 contiguous bytes. Non-temporal hints: input
// is read-once (256 MiB ~ L3 size), output never re-read.
//
// Use a native clang ext_vector_type — __builtin_nontemporal_load rejects
// HIP_vector_type structs (R2 compile error).

typedef float f32x4 __attribute__((ext_vector_type(4)));

__global__ __launch_bounds__(256) void bit2num_b4_kernel(
    const f32x4* __restrict__ x,   // x[j] = bits x[4j .. 4j+3]
    float* __restrict__ out,
    int n_out)
{
    int i = blockIdx.x * blockDim.x + threadIdx.x;
    const int stride = gridDim.x * blockDim.x;
    for (; i < n_out; i += stride) {
        const f32x4 v = __builtin_nontemporal_load(&x[i]);
        const float num =
            fmaf(8.f, v.x, fmaf(4.f, v.y, fmaf(2.f, v.z, v.w + 0.5f))) * 0.0625f;
        __builtin_nontemporal_store(num, &out[i]);
    }
}

extern "C" void kernel_launch(void* const* d_in, const int* in_sizes, int n_in,
                              void* d_out, int out_size, void* d_ws, size_t ws_size,
                              hipStream_t stream) {
    const float* x = (const float*)d_in[0];
    float* out = (float*)d_out;

    const int n_out = out_size;  // one output per group of 4 bits

    const int block = 256;
    int grid = (n_out + block - 1) / block;
    const int max_grid = 256 * 8;  // cap, grid-stride the rest
    if (grid > max_grid) grid = max_grid;

    bit2num_b4_kernel<<<grid, block, 0, stream>>>(
        (const f32x4*)x, out, n_out);
}